// Round 10
// baseline (235.195 us; speedup 1.0000x reference)
//
#include <hip/hip_runtime.h>
#include <hip/hip_bf16.h>

typedef __bf16 bf16x8 __attribute__((ext_vector_type(8)));
typedef float  f32x4  __attribute__((ext_vector_type(4)));

#define MFMA16 __builtin_amdgcn_mfma_f32_16x16x32_bf16

__device__ __forceinline__ float fast_tanh(float x) {
    float e = __builtin_amdgcn_exp2f(x * 2.8853900817779268f);
    return 1.0f - 2.0f * __builtin_amdgcn_rcpf(e + 1.0f);
}

// kappa permutation (within each 32-col block): stored k-index s -> phys col
__device__ __forceinline__ int kinv(int ke) {
    return (ke & ~31) | ((ke & 1) << 4) | ((ke >> 1) & 15);
}

__device__ __forceinline__ bf16x8 cvt2(const float4 a, const float4 b) {
    bf16x8 t;
    t[0] = (__bf16)a.x; t[1] = (__bf16)a.y; t[2] = (__bf16)a.z; t[3] = (__bf16)a.w;
    t[4] = (__bf16)b.x; t[5] = (__bf16)b.y; t[6] = (__bf16)b.z; t[7] = (__bf16)b.w;
    return t;
}

// ---- weight pre-conversion: f32 -> bf16 MFMA B-fragments in d_ws ----
// table1 ws[0,131072):      [cb:16][kk:8][lane:64][j:8 bf16]  (GEMM1, phys rows; cb = 16-col block)
// table2 ws[131072,196608): [q4:4][kk:8][nbl:2][lane:64][j:8] (GEMM2, kappa rows)
// table3 ws[196608,212992): [nb:4][kk:4][lane:64][j:8]        (GEMM3, identity rows)
__global__ __launch_bounds__(256) void preconv_kernel(
    const float* __restrict__ WFOH, const float* __restrict__ WFOM,
    const float* __restrict__ rhid2Layer, const float* __restrict__ routLayer,
    char* __restrict__ ws)
{
    const int f = blockIdx.x * 256 + threadIdx.x;
    bf16x8 v;
    char* dst;
    if (f < 8192) {
        const int lane = f & 63, t = f >> 6;
        const int kk = t & 7, cb = t >> 3;
        const int g = lane >> 4, c = lane & 15;
        const float* Wsrc = (cb < 8) ? WFOH : WFOM;
        const int col = (16 * cb + c) & 127;
        #pragma unroll
        for (int j = 0; j < 8; ++j) v[j] = (__bf16)Wsrc[(32 * kk + 8 * g + j) * 128 + col];
        dst = ws + (size_t)f * 16;
    } else if (f < 12288) {
        const int f2 = f - 8192;
        const int lane = f2 & 63, t = f2 >> 6;
        const int nbl = t & 1, kk = (t >> 1) & 7, q4 = t >> 4;
        const int g = lane >> 4, c = lane & 15;
        const int n2 = 32 * q4 + 16 * nbl + c;
        #pragma unroll
        for (int j = 0; j < 8; ++j) v[j] = (__bf16)rhid2Layer[kinv(32 * kk + 8 * g + j) * 128 + n2];
        dst = ws + 131072 + (size_t)f2 * 16;
    } else if (f < 13312) {
        const int f3 = f - 12288;
        const int lane = f3 & 63, t = f3 >> 6;
        const int kk = t & 3, nb = t >> 2;
        const int g = lane >> 4, c = lane & 15;
        const int n3 = 16 * nb + c;
        #pragma unroll
        for (int j = 0; j < 8; ++j) v[j] = (__bf16)routLayer[(32 * kk + 8 * g + j) * 64 + n3];
        dst = ws + 196608 + (size_t)f3 * 16;
    } else {
        return;
    }
    *(bf16x8*)dst = v;
}

template<bool PRE>
__device__ __forceinline__ bf16x8 wfrag1(const char* ws, const float* WFOH, const float* WFOM,
                                         int cb, int kk, int lane) {
    if constexpr (PRE) {
        return *(const bf16x8*)(ws + (size_t)cb * 8192 + kk * 1024 + lane * 16);
    } else {
        const int g = lane >> 4, c = lane & 15;
        const float* Wsrc = (cb < 8) ? WFOH : WFOM;
        const int col = (16 * cb + c) & 127;
        bf16x8 v;
        #pragma unroll
        for (int j = 0; j < 8; ++j) v[j] = (__bf16)Wsrc[(32 * kk + 8 * g + j) * 128 + col];
        return v;
    }
}
template<bool PRE>
__device__ __forceinline__ bf16x8 wfrag2(const char* ws, const float* rhid2Layer,
                                         int q4, int kk, int nbl, int lane) {
    if constexpr (PRE) {
        return *(const bf16x8*)(ws + 131072 + (size_t)q4 * 16384 + kk * 2048 + nbl * 1024 + lane * 16);
    } else {
        const int g = lane >> 4, c = lane & 15;
        const int n2 = 32 * q4 + 16 * nbl + c;
        bf16x8 v;
        #pragma unroll
        for (int j = 0; j < 8; ++j) v[j] = (__bf16)rhid2Layer[kinv(32 * kk + 8 * g + j) * 128 + n2];
        return v;
    }
}
template<bool PRE>
__device__ __forceinline__ bf16x8 wfrag3(const char* ws, const float* routLayer,
                                         int nb, int kk, int lane) {
    if constexpr (PRE) {
        return *(const bf16x8*)(ws + 196608 + (size_t)nb * 4096 + kk * 1024 + lane * 16);
    } else {
        const int g = lane >> 4, c = lane & 15;
        const int n3 = 16 * nb + c;
        bf16x8 v;
        #pragma unroll
        for (int j = 0; j < 8; ++j) v[j] = (__bf16)routLayer[(32 * kk + 8 * g + j) * 64 + n3];
        return v;
    }
}

// M_TILE=32, 256 threads (4 waves), 40KB LDS -> target 4 blocks/CU = 4
// independent barrier domains (block-level latency overlap, m114).
// 3 barriers/tile; GEMM3+hinge in-wave on waves 0-1.
template<bool PRE>
__global__ __launch_bounds__(256, 4) void rel_kernel(
    const float* __restrict__ fwd, const float* __restrict__ bwd,
    const int* __restrict__ gold_heads, const int* __restrict__ gold_rels,
    const float* __restrict__ WFOH, const float* __restrict__ WFOM,
    const float* __restrict__ rcatBias, const float* __restrict__ rhid2Layer,
    const float* __restrict__ rhid2Bias, const float* __restrict__ routLayer,
    const float* __restrict__ routBias, const char* __restrict__ wstab,
    int* __restrict__ fixcnt, int* __restrict__ fixlist, int fixcap,
    float* __restrict__ out, int E, int NT)
{
    __shared__ __align__(16) char smem[40960];
    char* const sh_cat = smem;            // 32 x 512B
    char* const sh_h   = smem + 16384;    // 32 x 512B (kappa cols)
    char* const sh_h2  = smem + 32768;    // 32 x 256B (identity cols)

    const int tid   = threadIdx.x;
    const int w     = tid >> 6;           // 0..3
    const int lane  = tid & 63;
    const int row16 = lane & 15;
    const int g     = lane >> 4;

    const int r_s = tid >> 3;             // staging row 0..31
    const int q_s = tid & 7;              // staging eighth (32 floats)

    float rcb[4], r2b[2], rob[4];
    #pragma unroll
    for (int nbl = 0; nbl < 4; ++nbl) rcb[nbl] = rcatBias[64 * w + 16 * nbl + row16];
    #pragma unroll
    for (int nbl = 0; nbl < 2; ++nbl) r2b[nbl] = rhid2Bias[32 * w + 16 * nbl + row16];
    #pragma unroll
    for (int nb = 0; nb < 4; ++nb) rob[nb] = routBias[16 * nb + row16];

    // ---- prologue gather for first tile ----
    bf16x8 pfb[4];
    {
        const int e = blockIdx.x * 32 + r_s;
        int nh0 = 0;
        if (q_s < 4 && e < E) nh0 = gold_heads[e];
        if (e < E) {
            const float* src = (q_s < 4) ? (fwd + (size_t)nh0 * 128 + 32 * q_s)
                                         : (bwd + (size_t)(e + 1) * 128 + 32 * (q_s - 4));
            const float4* p4 = (const float4*)src;
            #pragma unroll
            for (int i = 0; i < 4; ++i) pfb[i] = cvt2(p4[2 * i], p4[2 * i + 1]);
        } else {
            #pragma unroll
            for (int i = 0; i < 4; ++i) pfb[i] = cvt2(make_float4(0.f,0.f,0.f,0.f), make_float4(0.f,0.f,0.f,0.f));
        }
    }

    for (int tile = blockIdx.x; tile < NT; tile += gridDim.x) {
        const int e0 = tile * 32;
        const int tnext = tile + gridDim.x;
        const bool hn = tnext < NT;

        // opaque-zero launder: keeps weight-frag loads inside the tile loop
        int zoff = 0;
        asm volatile("" : "+v"(zoff));
        const char*  wsL  = wstab + zoff;
        const float* W1aL = WFOH + zoff;
        const float* W1bL = WFOM + zoff;
        const float* W2L  = rhid2Layer + zoff;
        const float* W3L  = routLayer + zoff;

        // next tile's head index first (latency overlaps staging + B1)
        int nh = 0; bool gv = false;
        if (hn) {
            const int en = tnext * 32 + r_s;
            gv = en < E;
            if (q_s < 4 && gv) nh = gold_heads[en];
        }

        // ---- stage cat tile (rotation swizzle: unit' = (u + row) & 31) ----
        #pragma unroll
        for (int i = 0; i < 4; ++i)
            *(bf16x8*)(sh_cat + r_s * 512 + 16 * ((4 * q_s + i + r_s) & 31)) = pfb[i];

        // gold labels (hinge rows 16w + 4g + i, waves 0-1)
        int gr[4] = {0, 0, 0, 0};
        if (w < 2) {
            #pragma unroll
            for (int i = 0; i < 4; ++i) {
                const int e = e0 + 16 * w + 4 * g + i;
                if (e < E) gr[i] = gold_rels[e];
            }
        }
        __syncthreads();                                   // B1: cat ready

        // ---- T14: issue next tile's gather batch A ----
        const float* gsrc = nullptr;
        if (hn) {
            gsrc = (q_s < 4) ? (fwd + (size_t)nh * 128 + 32 * q_s)
                             : (bwd + (size_t)(tnext * 32 + r_s + 1) * 128 + 32 * (q_s - 4));
        }
        float4 pfA[4];
        if (hn && gv) {
            const float4* p4 = (const float4*)gsrc;
            #pragma unroll
            for (int i = 0; i < 4; ++i) pfA[i] = p4[i];
        } else {
            #pragma unroll
            for (int i = 0; i < 4; ++i) pfA[i] = make_float4(0.f, 0.f, 0.f, 0.f);
        }

        // ---- GEMM1: h(32x256) = cat @ [WFOH|WFOM], tanh(+rcatBias) ----
        // wave w owns cols [64w, 64w+64) = col-blocks cb = 4w + nbl, nbl 0..3
        f32x4 acc1[2][4];
        #pragma unroll
        for (int mb = 0; mb < 2; ++mb)
            #pragma unroll
            for (int nbl = 0; nbl < 4; ++nbl) acc1[mb][nbl] = (f32x4){0.f, 0.f, 0.f, 0.f};
        __builtin_amdgcn_s_setprio(1);
        #pragma unroll
        for (int kk = 0; kk < 8; ++kk) {
            bf16x8 b[4];
            #pragma unroll
            for (int nbl = 0; nbl < 4; ++nbl)
                b[nbl] = wfrag1<PRE>(wsL, W1aL, W1bL, 4 * w + nbl, kk, lane);
            #pragma unroll
            for (int mb = 0; mb < 2; ++mb) {
                const int R = 16 * mb + row16;
                const bf16x8 a = *(const bf16x8*)(sh_cat + R * 512 + 16 * ((4 * kk + g + R) & 31));
                #pragma unroll
                for (int nbl = 0; nbl < 4; ++nbl)
                    acc1[mb][nbl] = MFMA16(a, b[nbl], acc1[mb][nbl], 0, 0, 0);
            }
        }
        __builtin_amdgcn_s_setprio(0);
        // epilogue: kappa pairs p in {0,1}: cols 64w+32p+16b+c, stored s = 64w+32p+2c+b
        #pragma unroll
        for (int mb = 0; mb < 2; ++mb) {
            #pragma unroll
            for (int p = 0; p < 2; ++p) {
                #pragma unroll
                for (int r = 0; r < 4; ++r) {
                    const int row = 16 * mb + 4 * g + r;
                    const __bf16 p0 = (__bf16)fast_tanh(acc1[mb][2 * p][r] + rcb[2 * p]);
                    const __bf16 p1 = (__bf16)fast_tanh(acc1[mb][2 * p + 1][r] + rcb[2 * p + 1]);
                    const unsigned uval = (unsigned)__builtin_bit_cast(unsigned short, p0)
                                        | ((unsigned)__builtin_bit_cast(unsigned short, p1) << 16);
                    const int u = 8 * w + 4 * p + (row16 >> 2);
                    *(unsigned*)(sh_h + row * 512 + 16 * ((u + row) & 31) + 4 * (row16 & 3)) = uval;
                }
            }
        }
        __syncthreads();                                   // B2: h ready

        // convert batch A -> pfb[0..1]; issue batch B
        pfb[0] = cvt2(pfA[0], pfA[1]);
        pfb[1] = cvt2(pfA[2], pfA[3]);
        float4 pfB[4];
        if (hn && gv) {
            const float4* p4 = (const float4*)gsrc;
            #pragma unroll
            for (int i = 0; i < 4; ++i) pfB[i] = p4[4 + i];
        } else {
            #pragma unroll
            for (int i = 0; i < 4; ++i) pfB[i] = make_float4(0.f, 0.f, 0.f, 0.f);
        }

        // ---- GEMM2: h2(32x128) = h @ W2(kappa), tanh(+rhid2Bias) ----
        // wave w owns h2-cols [32w, 32w+32), nbl 0..1
        f32x4 acc2[2][2];
        #pragma unroll
        for (int mb = 0; mb < 2; ++mb) {
            acc2[mb][0] = (f32x4){0.f, 0.f, 0.f, 0.f};
            acc2[mb][1] = (f32x4){0.f, 0.f, 0.f, 0.f};
        }
        __builtin_amdgcn_s_setprio(1);
        #pragma unroll
        for (int kk = 0; kk < 8; ++kk) {
            const bf16x8 b0 = wfrag2<PRE>(wsL, W2L, w, kk, 0, lane);
            const bf16x8 b1 = wfrag2<PRE>(wsL, W2L, w, kk, 1, lane);
            #pragma unroll
            for (int mb = 0; mb < 2; ++mb) {
                const int R = 16 * mb + row16;
                const bf16x8 a = *(const bf16x8*)(sh_h + R * 512 + 16 * ((4 * kk + g + R) & 31));
                acc2[mb][0] = MFMA16(a, b0, acc2[mb][0], 0, 0, 0);
                acc2[mb][1] = MFMA16(a, b1, acc2[mb][1], 0, 0, 0);
            }
        }
        __builtin_amdgcn_s_setprio(0);
        #pragma unroll
        for (int mb = 0; mb < 2; ++mb) {
            #pragma unroll
            for (int nbl = 0; nbl < 2; ++nbl) {
                #pragma unroll
                for (int r = 0; r < 4; ++r) {
                    const int row = 16 * mb + 4 * g + r;
                    const __bf16 p = (__bf16)fast_tanh(acc2[mb][nbl][r] + r2b[nbl]);
                    const int u2 = 4 * w + 2 * nbl + (row16 >> 3);
                    *(unsigned short*)(sh_h2 + row * 256 + 16 * ((u2 + row) & 15) + 2 * (row16 & 7))
                        = __builtin_bit_cast(unsigned short, p);
                }
            }
        }
        // convert batch B -> pfb[2..3]
        pfb[2] = cvt2(pfB[0], pfB[1]);
        pfb[3] = cvt2(pfB[2], pfB[3]);
        __syncthreads();                                   // B3: h2 ready

        // ---- GEMM3 + hinge fully in-wave (waves 0-1; 16 rows x 64 labels) ----
        if (w < 2) {
            const int R3 = 16 * w + row16;
            bf16x8 a3[4];
            #pragma unroll
            for (int kk = 0; kk < 4; ++kk)
                a3[kk] = *(const bf16x8*)(sh_h2 + R3 * 256 + 16 * ((4 * kk + g + R3) & 15));
            f32x4 acc3[4];
            __builtin_amdgcn_s_setprio(1);
            #pragma unroll
            for (int nb = 0; nb < 4; ++nb) {
                acc3[nb] = (f32x4){0.f, 0.f, 0.f, 0.f};
                #pragma unroll
                for (int kk = 0; kk < 4; ++kk) {
                    const bf16x8 b = wfrag3<PRE>(wsL, W3L, nb, kk, lane);
                    acc3[nb] = MFMA16(a3[kk], b, acc3[nb], 0, 0, 0);
                }
            }
            __builtin_amdgcn_s_setprio(0);
            #pragma unroll
            for (int i = 0; i < 4; ++i) {
                const int gold = gr[i];
                float gs = -3.0e38f, ws_ = -3.0e38f;
                #pragma unroll
                for (int nb = 0; nb < 4; ++nb) {
                    const float v = acc3[nb][i] + rob[nb];
                    const int lab = 16 * nb + row16;
                    if (lab == gold) gs = v; else ws_ = fmaxf(ws_, v);
                }
                gs = fmaxf(gs, __shfl_xor(gs, 1)); ws_ = fmaxf(ws_, __shfl_xor(ws_, 1));
                gs = fmaxf(gs, __shfl_xor(gs, 2)); ws_ = fmaxf(ws_, __shfl_xor(ws_, 2));
                gs = fmaxf(gs, __shfl_xor(gs, 4)); ws_ = fmaxf(ws_, __shfl_xor(ws_, 4));
                gs = fmaxf(gs, __shfl_xor(gs, 8)); ws_ = fmaxf(ws_, __shfl_xor(ws_, 8));
                const int e = e0 + 16 * w + 4 * g + i;
                if (row16 == 0 && e < E) {
                    out[e] = (gs < ws_ + 1.0f) ? (ws_ - gs) : 0.0f;
                    // hinge discontinuous at margin==1 -> exact f32 recompute
                    if (fabsf((gs - ws_) - 1.0f) < 0.125f && fixcap > 0) {
                        const int idx = atomicAdd(fixcnt, 1);
                        if (idx < fixcap) fixlist[idx] = e;
                    }
                }
            }
        }
        // no end barrier: loop-top staging writes cat (dead since B2);
        // B1' orders staging vs next GEMM1 readers.
    }
}

// ---- exact f32 recompute of margin-boundary edges (~1e-3 of edges) ----
__global__ __launch_bounds__(256) void fixup_kernel(
    const float* __restrict__ fwd, const float* __restrict__ bwd,
    const int* __restrict__ gold_heads, const int* __restrict__ gold_rels,
    const float* __restrict__ WFOH, const float* __restrict__ WFOM,
    const float* __restrict__ rcatBias, const float* __restrict__ rhid2Layer,
    const float* __restrict__ rhid2Bias, const float* __restrict__ routLayer,
    const float* __restrict__ routBias,
    const int* __restrict__ fixcnt, const int* __restrict__ fixlist, int fixcap,
    float* __restrict__ out)
{
    __shared__ float fx_cat[256];
    __shared__ float fx_h[256];
    __shared__ float fx_h2[128];
    __shared__ float fx_p[256];
    int n = *fixcnt;
    if (n > fixcap) n = fixcap;
    const int tid = threadIdx.x;
    for (int i = blockIdx.x; i < n; i += gridDim.x) {
        const int e = fixlist[i];
        {
            const int head = gold_heads[e];
            fx_cat[tid] = (tid < 128) ? fwd[(size_t)head * 128 + tid]
                                      : bwd[(size_t)(e + 1) * 128 + (tid - 128)];
        }
        __syncthreads();
        {
            const float* base = (tid < 128) ? WFOH : WFOM;
            const int col = tid & 127;
            float s = 0.f;
            #pragma unroll 8
            for (int k = 0; k < 256; ++k) s += fx_cat[k] * base[k * 128 + col];
            fx_h[tid] = tanhf(s + rcatBias[tid]);
        }
        __syncthreads();
        {
            const int d = tid & 127, hh = tid >> 7;
            float s = 0.f;
            #pragma unroll 8
            for (int k = 128 * hh; k < 128 * hh + 128; ++k) s += fx_h[k] * rhid2Layer[k * 128 + d];
            fx_p[hh * 128 + d] = s;
        }
        __syncthreads();
        if (tid < 128) fx_h2[tid] = tanhf(fx_p[tid] + fx_p[128 + tid] + rhid2Bias[tid]);
        __syncthreads();
        {
            const int d = tid & 63, qq = tid >> 6;
            float s = 0.f;
            #pragma unroll 8
            for (int k = 32 * qq; k < 32 * qq + 32; ++k) s += fx_h2[k] * routLayer[k * 64 + d];
            fx_p[qq * 64 + d] = s;
        }
        __syncthreads();
        if (tid < 64) {
            const float v = fx_p[tid] + fx_p[64 + tid] + fx_p[128 + tid] + fx_p[192 + tid] + routBias[tid];
            const int gold = gold_rels[e];
            float gs = (tid == gold) ? v : -3.0e38f;
            float wv = (tid == gold) ? -3.0e38f : v;
            #pragma unroll
            for (int o = 1; o < 64; o <<= 1) {
                gs = fmaxf(gs, __shfl_xor(gs, o));
                wv = fmaxf(wv, __shfl_xor(wv, o));
            }
            if (tid == 0) out[e] = (gs < wv + 1.0f) ? (wv - gs) : 0.0f;
        }
        __syncthreads();
    }
}

extern "C" void kernel_launch(void* const* d_in, const int* in_sizes, int n_in,
                              void* d_out, int out_size, void* d_ws, size_t ws_size,
                              hipStream_t stream) {
    const float* fwd        = (const float*)d_in[0];
    const float* bwd        = (const float*)d_in[1];
    const int*   gold_heads = (const int*)d_in[2];
    const int*   gold_rels  = (const int*)d_in[3];
    const float* WFOH       = (const float*)d_in[4];
    const float* WFOM       = (const float*)d_in[5];
    const float* rcatBias   = (const float*)d_in[7];   // d_in[6] rhidBias unused by reference
    const float* rhid2      = (const float*)d_in[8];
    const float* rhid2Bias  = (const float*)d_in[9];
    const float* rout       = (const float*)d_in[10];
    const float* routBias   = (const float*)d_in[11];
    float* out = (float*)d_out;

    const int E = in_sizes[2];
    if (E <= 0) return;
    const int NT = (E + 31) / 32;
    const int grid = NT < 1024 ? NT : 1024;

    const size_t TAB = 212992;
    const int FIXCAP = 8192;
    const size_t FIX_BYTES = 4 + 4 * (size_t)FIXCAP;

    const bool pre = ws_size >= TAB + FIX_BYTES;
    int* fixcnt = nullptr;
    int* fixlist = nullptr;
    int fixcap = 0;
    if (pre) {
        fixcnt = (int*)((char*)d_ws + TAB);
        fixlist = fixcnt + 1;
        fixcap = FIXCAP;
    } else if (ws_size >= FIX_BYTES) {
        fixcnt = (int*)d_ws;
        fixlist = fixcnt + 1;
        fixcap = FIXCAP;
    }
    if (fixcap) hipMemsetAsync(fixcnt, 0, 4, stream);

    if (pre) {
        hipLaunchKernelGGL(preconv_kernel, dim3(52), dim3(256), 0, stream,
                           WFOH, WFOM, rhid2, rout, (char*)d_ws);
        hipLaunchKernelGGL((rel_kernel<true>), dim3(grid), dim3(256), 0, stream,
                           fwd, bwd, gold_heads, gold_rels, WFOH, WFOM, rcatBias,
                           rhid2, rhid2Bias, rout, routBias, (const char*)d_ws,
                           fixcnt, fixlist, fixcap, out, E, NT);
    } else {
        hipLaunchKernelGGL((rel_kernel<false>), dim3(grid), dim3(256), 0, stream,
                           fwd, bwd, gold_heads, gold_rels, WFOH, WFOM, rcatBias,
                           rhid2, rhid2Bias, rout, routBias, (const char*)nullptr,
                           fixcnt, fixlist, fixcap, out, E, NT);
    }
    if (fixcap) {
        hipLaunchKernelGGL(fixup_kernel, dim3(120), dim3(256), 0, stream,
                           fwd, bwd, gold_heads, gold_rels, WFOH, WFOM, rcatBias,
                           rhid2, rhid2Bias, rout, routBias,
                           fixcnt, fixlist, fixcap, out);
    }
}

// Round 11
// 224.618 us; speedup vs baseline: 1.0471x; 1.0471x over previous
//
#include <hip/hip_runtime.h>
#include <hip/hip_bf16.h>

typedef __bf16 bf16x8 __attribute__((ext_vector_type(8)));
typedef float  f32x4  __attribute__((ext_vector_type(4)));

#define MFMA16 __builtin_amdgcn_mfma_f32_16x16x32_bf16

__device__ __forceinline__ float fast_tanh(float x) {
    float e = __builtin_amdgcn_exp2f(x * 2.8853900817779268f);
    return 1.0f - 2.0f * __builtin_amdgcn_rcpf(e + 1.0f);
}

// kappa permutation (within each 32-col block): stored k-index s -> phys col
__device__ __forceinline__ int kinv(int ke) {
    return (ke & ~31) | ((ke & 1) << 4) | ((ke >> 1) & 15);
}

__device__ __forceinline__ bf16x8 cvt2(const float4 a, const float4 b) {
    bf16x8 t;
    t[0] = (__bf16)a.x; t[1] = (__bf16)a.y; t[2] = (__bf16)a.z; t[3] = (__bf16)a.w;
    t[4] = (__bf16)b.x; t[5] = (__bf16)b.y; t[6] = (__bf16)b.z; t[7] = (__bf16)b.w;
    return t;
}

// ---- weight pre-conversion: f32 -> bf16 MFMA B-fragments in d_ws ----
// table1 ws[0,131072):      [cb:16][kk:8][lane:64][j:8 bf16]  (GEMM1, phys rows)
// table2 ws[131072,196608): [q4:4][kk:8][nbl:2][lane:64][j:8] (GEMM2, kappa rows)
// table3 ws[196608,212992): [nb:4][kk:4][lane:64][j:8]        (GEMM3, kappa rows)
__global__ __launch_bounds__(256) void preconv_kernel(
    const float* __restrict__ WFOH, const float* __restrict__ WFOM,
    const float* __restrict__ rhid2Layer, const float* __restrict__ routLayer,
    char* __restrict__ ws)
{
    const int f = blockIdx.x * 256 + threadIdx.x;
    bf16x8 v;
    char* dst;
    if (f < 8192) {
        const int lane = f & 63, t = f >> 6;
        const int kk = t & 7, cb = t >> 3;
        const int g = lane >> 4, c = lane & 15;
        const float* Wsrc = (cb < 8) ? WFOH : WFOM;
        const int col = (16 * cb + c) & 127;
        #pragma unroll
        for (int j = 0; j < 8; ++j) v[j] = (__bf16)Wsrc[(32 * kk + 8 * g + j) * 128 + col];
        dst = ws + (size_t)f * 16;
    } else if (f < 12288) {
        const int f2 = f - 8192;
        const int lane = f2 & 63, t = f2 >> 6;
        const int nbl = t & 1, kk = (t >> 1) & 7, q4 = t >> 4;
        const int g = lane >> 4, c = lane & 15;
        const int n2 = 32 * q4 + 16 * nbl + c;
        #pragma unroll
        for (int j = 0; j < 8; ++j) v[j] = (__bf16)rhid2Layer[kinv(32 * kk + 8 * g + j) * 128 + n2];
        dst = ws + 131072 + (size_t)f2 * 16;
    } else if (f < 13312) {
        const int f3 = f - 12288;
        const int lane = f3 & 63, t = f3 >> 6;
        const int kk = t & 3, nb = t >> 2;
        const int g = lane >> 4, c = lane & 15;
        const int n3 = 16 * nb + c;
        #pragma unroll
        for (int j = 0; j < 8; ++j) v[j] = (__bf16)routLayer[kinv(32 * kk + 8 * g + j) * 64 + n3];
        dst = ws + 196608 + (size_t)f3 * 16;
    } else {
        return;
    }
    *(bf16x8*)dst = v;
}

template<bool PRE>
__device__ __forceinline__ bf16x8 wfrag1(const char* ws, const float* WFOH, const float* WFOM,
                                         int cb, int kk, int lane) {
    if constexpr (PRE) {
        return *(const bf16x8*)(ws + (size_t)cb * 8192 + kk * 1024 + lane * 16);
    } else {
        const int g = lane >> 4, c = lane & 15;
        const float* Wsrc = (cb < 8) ? WFOH : WFOM;
        const int col = (16 * cb + c) & 127;
        bf16x8 v;
        #pragma unroll
        for (int j = 0; j < 8; ++j) v[j] = (__bf16)Wsrc[(32 * kk + 8 * g + j) * 128 + col];
        return v;
    }
}
template<bool PRE>
__device__ __forceinline__ bf16x8 wfrag2(const char* ws, const float* rhid2Layer,
                                         int q4, int kk, int nbl, int lane) {
    if constexpr (PRE) {
        return *(const bf16x8*)(ws + 131072 + (size_t)q4 * 16384 + kk * 2048 + nbl * 1024 + lane * 16);
    } else {
        const int g = lane >> 4, c = lane & 15;
        const int n2 = 32 * q4 + 16 * nbl + c;
        bf16x8 v;
        #pragma unroll
        for (int j = 0; j < 8; ++j) v[j] = (__bf16)rhid2Layer[kinv(32 * kk + 8 * g + j) * 128 + n2];
        return v;
    }
}
template<bool PRE>
__device__ __forceinline__ bf16x8 wfrag3(const char* ws, const float* routLayer,
                                         int nb, int kk, int lane) {
    if constexpr (PRE) {
        return *(const bf16x8*)(ws + 196608 + (size_t)nb * 4096 + kk * 1024 + lane * 16);
    } else {
        const int g = lane >> 4, c = lane & 15;
        const int n3 = 16 * nb + c;
        bf16x8 v;
        #pragma unroll
        for (int j = 0; j < 8; ++j) v[j] = (__bf16)routLayer[kinv(32 * kk + 8 * g + j) * 64 + n3];
        return v;
    }
}

// ZERO-BARRIER kernel: one wave owns 16 edges end-to-end.
// 512 threads = 8 independent waves; 8KB wave-private LDS each (64KB/block);
// cat A-frags load directly from global; C->A transposes via private LDS
// (same-wave, lgkmcnt only — no __syncthreads in the entire kernel).
template<bool PRE>
__global__ __launch_bounds__(512, 2) void rel_kernel(
    const float* __restrict__ fwd, const float* __restrict__ bwd,
    const int* __restrict__ gold_heads, const int* __restrict__ gold_rels,
    const float* __restrict__ WFOH, const float* __restrict__ WFOM,
    const float* __restrict__ rcatBias, const float* __restrict__ rhid2Layer,
    const float* __restrict__ rhid2Bias, const float* __restrict__ routLayer,
    const float* __restrict__ routBias, const char* __restrict__ wstab,
    int* __restrict__ fixcnt, int* __restrict__ fixlist, int fixcap,
    float* __restrict__ out, int E, int NT16)
{
    __shared__ __align__(16) char smem[65536];
    const int tid   = threadIdx.x;
    const int w     = tid >> 6;
    const int lane  = tid & 63;
    const int row16 = lane & 15;
    const int g     = lane >> 4;
    char* const myh = smem + w * 8192;   // wave-private scratch

    for (int tile = blockIdx.x * 8 + w; tile < NT16; tile += gridDim.x * 8) {
        const int e0 = tile * 16;

        // laundered pointers: keep weight/bias loads inside the tile loop
        int zoff = 0;
        asm volatile("" : "+v"(zoff));
        const char*  wsL  = wstab + zoff;
        const float* W1aL = WFOH + zoff;
        const float* W1bL = WFOM + zoff;
        const float* W2L  = rhid2Layer + zoff;
        const float* W3L  = routLayer + zoff;
        const float* rcL  = rcatBias + zoff;
        const float* r2L  = rhid2Bias + zoff;
        const float* roL  = routBias + zoff;

        // ---- cat A-frags directly from global (lane = row row16) ----
        const int er = e0 + row16;
        const bool ev = er < E;
        const int head = ev ? gold_heads[er] : 0;
        const float* frow = fwd + (size_t)head * 128;
        const float* brow = bwd + (ev ? (size_t)(er + 1) * 128 : (size_t)0);
        bf16x8 a[8];
        #pragma unroll
        for (int kk = 0; kk < 4; ++kk) {
            const float4* p = (const float4*)(frow + 32 * kk + 8 * g);
            a[kk] = cvt2(p[0], p[1]);
        }
        #pragma unroll
        for (int kk = 0; kk < 4; ++kk) {
            const float4* p = (const float4*)(brow + 32 * kk + 8 * g);
            a[4 + kk] = cvt2(p[0], p[1]);
        }

        // ---- GEMM1: h(16x256), two n-halves of 8 col-blocks ----
        #pragma unroll
        for (int half = 0; half < 2; ++half) {
            f32x4 acc[8];
            #pragma unroll
            for (int j = 0; j < 8; ++j) {
                const float b = rcL[16 * (8 * half + j) + row16];   // bias-splat init
                acc[j] = (f32x4){b, b, b, b};
            }
            __builtin_amdgcn_s_setprio(1);
            #pragma unroll
            for (int kk = 0; kk < 8; ++kk) {
                #pragma unroll
                for (int j = 0; j < 8; ++j) {
                    const bf16x8 b = wfrag1<PRE>(wsL, W1aL, W1bL, 8 * half + j, kk, lane);
                    acc[j] = MFMA16(a[kk], b, acc[j], 0, 0, 0);
                }
            }
            __builtin_amdgcn_s_setprio(0);
            // tanh + kappa-pack -> wave-private LDS (rows 512B, rotation swizzle)
            #pragma unroll
            for (int q = 0; q < 4; ++q) {
                const int qq = 4 * half + q;
                #pragma unroll
                for (int r = 0; r < 4; ++r) {
                    const int row = 4 * g + r;
                    const __bf16 p0 = (__bf16)fast_tanh(acc[2 * q][r]);
                    const __bf16 p1 = (__bf16)fast_tanh(acc[2 * q + 1][r]);
                    const unsigned uval = (unsigned)__builtin_bit_cast(unsigned short, p0)
                                        | ((unsigned)__builtin_bit_cast(unsigned short, p1) << 16);
                    const int u = 4 * qq + (row16 >> 2);
                    *(unsigned*)(myh + row * 512 + 16 * ((u + row) & 31) + 4 * (row16 & 3)) = uval;
                }
            }
        }

        // ---- h A-frags back from LDS (same wave: lgkmcnt only) ----
        #pragma unroll
        for (int kk = 0; kk < 8; ++kk)
            a[kk] = *(const bf16x8*)(myh + row16 * 512 + 16 * ((4 * kk + g + row16) & 31));

        // ---- GEMM2: h2(16x128), 8 col-blocks ----
        f32x4 acc2[8];
        #pragma unroll
        for (int j = 0; j < 8; ++j) {
            const float b = r2L[16 * j + row16];
            acc2[j] = (f32x4){b, b, b, b};
        }
        __builtin_amdgcn_s_setprio(1);
        #pragma unroll
        for (int kk = 0; kk < 8; ++kk) {
            #pragma unroll
            for (int j = 0; j < 8; ++j) {
                const bf16x8 b = wfrag2<PRE>(wsL, W2L, j >> 1, kk, j & 1, lane);
                acc2[j] = MFMA16(a[kk], b, acc2[j], 0, 0, 0);
            }
        }
        __builtin_amdgcn_s_setprio(0);
        // tanh + kappa-pack h2 into myh (rows 256B now; h region dead)
        #pragma unroll
        for (int q = 0; q < 4; ++q) {
            #pragma unroll
            for (int r = 0; r < 4; ++r) {
                const int row = 4 * g + r;
                const __bf16 p0 = (__bf16)fast_tanh(acc2[2 * q][r]);
                const __bf16 p1 = (__bf16)fast_tanh(acc2[2 * q + 1][r]);
                const unsigned uval = (unsigned)__builtin_bit_cast(unsigned short, p0)
                                    | ((unsigned)__builtin_bit_cast(unsigned short, p1) << 16);
                const int u2 = 4 * q + (row16 >> 2);
                *(unsigned*)(myh + row * 256 + 16 * ((u2 + row) & 15) + 4 * (row16 & 3)) = uval;
            }
        }

        // ---- h2 A-frags ----
        bf16x8 a3[4];
        #pragma unroll
        for (int kk = 0; kk < 4; ++kk)
            a3[kk] = *(const bf16x8*)(myh + row16 * 256 + 16 * ((4 * kk + g + row16) & 15));

        // ---- GEMM3: sc(16x64) + in-wave hinge ----
        f32x4 acc3[4];
        #pragma unroll
        for (int j = 0; j < 4; ++j) {
            const float b = roL[16 * j + row16];
            acc3[j] = (f32x4){b, b, b, b};
        }
        __builtin_amdgcn_s_setprio(1);
        #pragma unroll
        for (int kk = 0; kk < 4; ++kk) {
            #pragma unroll
            for (int j = 0; j < 4; ++j) {
                const bf16x8 b = wfrag3<PRE>(wsL, W3L, j, kk, lane);
                acc3[j] = MFMA16(a3[kk], b, acc3[j], 0, 0, 0);
            }
        }
        __builtin_amdgcn_s_setprio(0);
        #pragma unroll
        for (int r = 0; r < 4; ++r) {
            const int e = e0 + 4 * g + r;
            const int gold = (e < E) ? gold_rels[e] : 0;
            float gs = -3.0e38f, ws_ = -3.0e38f;
            #pragma unroll
            for (int nb = 0; nb < 4; ++nb) {
                const float v = acc3[nb][r];
                const int lab = 16 * nb + row16;
                if (lab == gold) gs = v; else ws_ = fmaxf(ws_, v);
            }
            gs = fmaxf(gs, __shfl_xor(gs, 1)); ws_ = fmaxf(ws_, __shfl_xor(ws_, 1));
            gs = fmaxf(gs, __shfl_xor(gs, 2)); ws_ = fmaxf(ws_, __shfl_xor(ws_, 2));
            gs = fmaxf(gs, __shfl_xor(gs, 4)); ws_ = fmaxf(ws_, __shfl_xor(ws_, 4));
            gs = fmaxf(gs, __shfl_xor(gs, 8)); ws_ = fmaxf(ws_, __shfl_xor(ws_, 8));
            if (row16 == 0 && e < E) {
                out[e] = (gs < ws_ + 1.0f) ? (ws_ - gs) : 0.0f;
                // hinge discontinuous at margin==1 -> exact f32 recompute later
                if (fabsf((gs - ws_) - 1.0f) < 0.125f && fixcap > 0) {
                    const int idx = atomicAdd(fixcnt, 1);
                    if (idx < fixcap) fixlist[idx] = e;
                }
            }
        }
        // next iteration reuses myh: same wave, compiler orders via lgkmcnt.
    }
}

// ---- exact f32 recompute of margin-boundary edges (~1e-3 of edges) ----
__global__ __launch_bounds__(256) void fixup_kernel(
    const float* __restrict__ fwd, const float* __restrict__ bwd,
    const int* __restrict__ gold_heads, const int* __restrict__ gold_rels,
    const float* __restrict__ WFOH, const float* __restrict__ WFOM,
    const float* __restrict__ rcatBias, const float* __restrict__ rhid2Layer,
    const float* __restrict__ rhid2Bias, const float* __restrict__ routLayer,
    const float* __restrict__ routBias,
    const int* __restrict__ fixcnt, const int* __restrict__ fixlist, int fixcap,
    float* __restrict__ out)
{
    __shared__ float fx_cat[256];
    __shared__ float fx_h[256];
    __shared__ float fx_h2[128];
    __shared__ float fx_p[256];
    int n = *fixcnt;
    if (n > fixcap) n = fixcap;
    const int tid = threadIdx.x;
    for (int i = blockIdx.x; i < n; i += gridDim.x) {
        const int e = fixlist[i];
        {
            const int head = gold_heads[e];
            fx_cat[tid] = (tid < 128) ? fwd[(size_t)head * 128 + tid]
                                      : bwd[(size_t)(e + 1) * 128 + (tid - 128)];
        }
        __syncthreads();
        {
            const float* base = (tid < 128) ? WFOH : WFOM;
            const int col = tid & 127;
            float s = 0.f;
            #pragma unroll 8
            for (int k = 0; k < 256; ++k) s += fx_cat[k] * base[k * 128 + col];
            fx_h[tid] = tanhf(s + rcatBias[tid]);
        }
        __syncthreads();
        {
            const int d = tid & 127, hh = tid >> 7;
            float s = 0.f;
            #pragma unroll 8
            for (int k = 128 * hh; k < 128 * hh + 128; ++k) s += fx_h[k] * rhid2Layer[k * 128 + d];
            fx_p[hh * 128 + d] = s;
        }
        __syncthreads();
        if (tid < 128) fx_h2[tid] = tanhf(fx_p[tid] + fx_p[128 + tid] + rhid2Bias[tid]);
        __syncthreads();
        {
            const int d = tid & 63, qq = tid >> 6;
            float s = 0.f;
            #pragma unroll 8
            for (int k = 32 * qq; k < 32 * qq + 32; ++k) s += fx_h2[k] * routLayer[k * 64 + d];
            fx_p[qq * 64 + d] = s;
        }
        __syncthreads();
        if (tid < 64) {
            const float v = fx_p[tid] + fx_p[64 + tid] + fx_p[128 + tid] + fx_p[192 + tid] + routBias[tid];
            const int gold = gold_rels[e];
            float gs = (tid == gold) ? v : -3.0e38f;
            float wv = (tid == gold) ? -3.0e38f : v;
            #pragma unroll
            for (int o = 1; o < 64; o <<= 1) {
                gs = fmaxf(gs, __shfl_xor(gs, o));
                wv = fmaxf(wv, __shfl_xor(wv, o));
            }
            if (tid == 0) out[e] = (gs < wv + 1.0f) ? (wv - gs) : 0.0f;
        }
        __syncthreads();
    }
}

extern "C" void kernel_launch(void* const* d_in, const int* in_sizes, int n_in,
                              void* d_out, int out_size, void* d_ws, size_t ws_size,
                              hipStream_t stream) {
    const float* fwd        = (const float*)d_in[0];
    const float* bwd        = (const float*)d_in[1];
    const int*   gold_heads = (const int*)d_in[2];
    const int*   gold_rels  = (const int*)d_in[3];
    const float* WFOH       = (const float*)d_in[4];
    const float* WFOM       = (const float*)d_in[5];
    const float* rcatBias   = (const float*)d_in[7];   // d_in[6] rhidBias unused by reference
    const float* rhid2      = (const float*)d_in[8];
    const float* rhid2Bias  = (const float*)d_in[9];
    const float* rout       = (const float*)d_in[10];
    const float* routBias   = (const float*)d_in[11];
    float* out = (float*)d_out;

    const int E = in_sizes[2];
    if (E <= 0) return;
    const int NT16 = (E + 15) / 16;
    int grid = (NT16 + 7) / 8;
    if (grid > 2048) grid = 2048;

    const size_t TAB = 212992;
    const int FIXCAP = 8192;
    const size_t FIX_BYTES = 4 + 4 * (size_t)FIXCAP;

    const bool pre = ws_size >= TAB + FIX_BYTES;
    int* fixcnt = nullptr;
    int* fixlist = nullptr;
    int fixcap = 0;
    if (pre) {
        fixcnt = (int*)((char*)d_ws + TAB);
        fixlist = fixcnt + 1;
        fixcap = FIXCAP;
    } else if (ws_size >= FIX_BYTES) {
        fixcnt = (int*)d_ws;
        fixlist = fixcnt + 1;
        fixcap = FIXCAP;
    }
    if (fixcap) hipMemsetAsync(fixcnt, 0, 4, stream);

    if (pre) {
        hipLaunchKernelGGL(preconv_kernel, dim3(52), dim3(256), 0, stream,
                           WFOH, WFOM, rhid2, rout, (char*)d_ws);
        hipLaunchKernelGGL((rel_kernel<true>), dim3(grid), dim3(512), 0, stream,
                           fwd, bwd, gold_heads, gold_rels, WFOH, WFOM, rcatBias,
                           rhid2, rhid2Bias, rout, routBias, (const char*)d_ws,
                           fixcnt, fixlist, fixcap, out, E, NT16);
    } else {
        hipLaunchKernelGGL((rel_kernel<false>), dim3(grid), dim3(512), 0, stream,
                           fwd, bwd, gold_heads, gold_rels, WFOH, WFOM, rcatBias,
                           rhid2, rhid2Bias, rout, routBias, (const char*)nullptr,
                           fixcnt, fixlist, fixcap, out, E, NT16);
    }
    if (fixcap) {
        hipLaunchKernelGGL(fixup_kernel, dim3(120), dim3(256), 0, stream,
                           fwd, bwd, gold_heads, gold_rels, WFOH, WFOM, rcatBias,
                           rhid2, rhid2Bias, rout, routBias,
                           fixcnt, fixlist, fixcap, out);
    }
}